// Round 17
// baseline (47.543 us; speedup 1.0000x reference)
//
#include <hip/hip_runtime.h>

#define KN      1024
#define FAN_IN  16
#define NSP     64
#define MAPB    (NSP * NSP)
#define THRESH  12

__device__ __forceinline__ float tanh_fast(float x) {
    float ax = fabsf(x);
    float e  = __expf(-2.0f * ax);
    float r  = 1.0f - 2.0f * e * __builtin_amdgcn_rcpf(1.0f + e);
    return copysignf(r, x);
}

// Full-wave DPP shifts; bound_ctrl=1 zeroes shifted-in edge lane = conv zero-pad
// at col 0 / col 63. Proven R9/R10.
__device__ __forceinline__ float dpp_wshr1(float x) {
    return __int_as_float(__builtin_amdgcn_update_dpp(
        0, __float_as_int(x), 0x138, 0xF, 0xF, true));
}
__device__ __forceinline__ float dpp_wshl1(float x) {
    return __int_as_float(__builtin_amdgcn_update_dpp(
        0, __float_as_int(x), 0x130, 0xF, 0xF, true));
}

__device__ __forceinline__ unsigned short f2bf_rne(float x) {
    unsigned u = __float_as_uint(x);
    return (unsigned short)((u + 0x7FFFu + ((u >> 16) & 1u)) >> 16);
}
__device__ __forceinline__ float bf2f(unsigned short s) {
    return __uint_as_float(((unsigned)s) << 16);
}

// ---- pre-pass: f32 maps -> bf16 maps in d_ws (RNE). Proven R10. ----
__global__ __launch_bounds__(256) void compress_kernel(
    const float* __restrict__ in, unsigned short* __restrict__ out16)
{
    const int i = (blockIdx.x * 256 + threadIdx.x) * 4;
    float4 v = *(const float4*)(in + i);
    ushort4 o;
    o.x = f2bf_rne(v.x); o.y = f2bf_rne(v.y);
    o.z = f2bf_rne(v.z); o.w = f2bf_rne(v.w);
    *(ushort4*)(out16 + i) = o;
}

// ---- main: 2048 blocks (2 spatial halves per node), 256 threads (4 waves).
// Wave wv owns output rows h*32+wv*8 .. +7; lane = column. Per channel:
// ONE global_load_lds issue stages the block's 32 rows (4 KB bf16; wave wv's
// dest = sbuf + wv*1024B, src = map + h*4096 + tid*16 — HW writes dest+lane*16);
// the 2 block-edge halo rows come from per-lane register loads. Double-buffered,
// one __syncthreads per channel (R9-proven). 16 barrier domains per CU.
__global__ __launch_bounds__(256) void decoder_bf16(
    const unsigned short* __restrict__ maps16,   // [1024][4096] bf16 (d_ws)
    const void*  __restrict__ prev_is_active,
    const int*   __restrict__ parent_indices,
    const float* __restrict__ Wt,
    const float* __restrict__ bias,
    float*       __restrict__ out)
{
    __shared__ unsigned short sbuf[2][32 * NSP]; // 2 x 4 KB

    const int bid  = blockIdx.x;
    const int k    = bid >> 1;
    const int h    = bid & 1;                    // row half
    const int tid  = threadIdx.x;
    const int lane = tid & 63;                   // column
    const int wv   = tid >> 6;                   // 0..3
    const int r0   = h * 32 + wv * 8;            // first global output row

    // --- sniff flag encoding (deterministic) ---
    bool bytemode = false;
    {
        const unsigned* sv = (const unsigned*)prev_is_active;
        #pragma unroll
        for (int i = 0; i < 16; ++i)
            if (sv[i] > 1u) bytemode = true;
    }

    // --- activity gate (uniform) ---
    const int* pidx = parent_indices + k * FAN_IN;
    int cnt = 0;
    #pragma unroll
    for (int i = 0; i < FAN_IN; ++i) {
        int p = pidx[i];
        int f;
        if (bytemode) f = (((const unsigned char*)prev_is_active)[p] != 0);
        else          f = (((const int*)prev_is_active)[p] != 0);
        cnt += f;
    }
    const bool active = (cnt >= THRESH);

    const size_t obase = (size_t)k * MAPB;
    if (h == 0 && tid == 0)
        out[(size_t)KN * MAPB + k] = active ? 1.0f : 0.0f;

    if (!active) {                   // uniform early-exit: no barriers executed
        float4 z = make_float4(0.f, 0.f, 0.f, 0.f);
        float4* o4 = (float4*)(out + obase + (size_t)h * 32 * NSP);
        o4[tid]       = z;
        o4[tid + 256] = z;
        return;
    }

    // block-edge halo machinery (value-masked; clamped addresses)
    const float mT = (h == 1) ? 1.0f : 0.0f;     // global row h*32-1 valid?
    const float mB = (h == 0) ? 1.0f : 0.0f;     // global row h*32+32 valid?
    const int   haloTrow = (h == 1) ? 31 : 0;    // clamped global row h*32-1
    const int   haloBrow = (h == 0) ? 32 : 63;   // clamped global row h*32+32

    const float* wbase = Wt + (size_t)k * FAN_IN * 9;

    float acc[8];
    #pragma unroll
    for (int s = 0; s < 8; ++s) acc[s] = 0.0f;

    unsigned short hT_n, hB_n;

    // stage channel ch into sbuf[b]: 1 DMA issue + 2 halo reg loads
#define STAGE(b, ch)                                                          \
    {                                                                         \
        const size_t pb = (size_t)pidx[ch] * MAPB;                            \
        __builtin_amdgcn_global_load_lds(                                     \
            (const __attribute__((address_space(1))) unsigned*)               \
                ((const char*)maps16 + pb * 2 + h * 4096 + tid * 16),         \
            (__attribute__((address_space(3))) unsigned*)                     \
                ((char*)&sbuf[b][0] + wv * 1024),                             \
            16, 0, 0);                                                        \
        hT_n = maps16[pb + haloTrow * NSP + lane];                            \
        hB_n = maps16[pb + haloBrow * NSP + lane];                            \
    }

    STAGE(0, 0);
    __syncthreads();                 // drain DMA + halo loads: buf0 ready

    #pragma unroll 2
    for (int ch = 0; ch < FAN_IN; ++ch) {
        const unsigned short hT = hT_n, hB = hB_n;   // completed at last barrier
        if (ch + 1 < FAN_IN) STAGE((ch + 1) & 1, ch + 1);

        const unsigned short* sb = sbuf[ch & 1];
        const float* w = wbase + ch * 9;             // uniform -> s_loads
        const float wl0 = w[0], wc0 = w[1], wr0 = w[2];
        const float wl1 = w[3], wc1 = w[4], wr1 = w[5];
        const float wl2 = w[6], wc2 = w[7], wr2 = w[8];

        // v[j] = input global row r0-1+j, this lane's column (local rows wv*8-1..wv*8+8)
        const int lT = (wv > 0) ? wv * 8 - 1 : 0;    // clamped local (unused if wv==0)
        const int lB = (wv < 3) ? wv * 8 + 8 : 31;   // clamped local (unused if wv==3)
        float v[10], l[10], r[10];
        v[0] = (wv == 0) ? bf2f(hT) * mT : bf2f(sb[lT * NSP + lane]);
        #pragma unroll
        for (int j = 1; j <= 8; ++j) v[j] = bf2f(sb[(wv * 8 - 1 + j) * NSP + lane]);
        v[9] = (wv == 3) ? bf2f(hB) * mB : bf2f(sb[lB * NSP + lane]);
        #pragma unroll
        for (int j = 0; j < 10; ++j) { l[j] = dpp_wshr1(v[j]); r[j] = dpp_wshl1(v[j]); }

        #pragma unroll
        for (int s = 0; s < 8; ++s) {
            float a = acc[s];
            a = fmaf(wl0, l[s],     fmaf(wc0, v[s],     fmaf(wr0, r[s],     a)));
            a = fmaf(wl1, l[s + 1], fmaf(wc1, v[s + 1], fmaf(wr1, r[s + 1], a)));
            a = fmaf(wl2, l[s + 2], fmaf(wc2, v[s + 2], fmaf(wr2, r[s + 2], a)));
            acc[s] = a;
        }

        if (ch + 1 < FAN_IN) __syncthreads();        // drain prefetch + handoff
    }
#undef STAGE

    const float bk = bias[k];
    #pragma unroll
    for (int s = 0; s < 8; ++s)
        out[obase + (size_t)(r0 + s) * NSP + lane] = tanh_fast(acc[s] + bk);
}

// ---- f32 fallback (R9 verbatim, proven 39.1 us) if ws too small ----
__device__ __forceinline__ void gload_lds16f(const float* g, float* l) {
    __builtin_amdgcn_global_load_lds(
        (const __attribute__((address_space(1))) unsigned*)g,
        (__attribute__((address_space(3)))       unsigned*)l,
        16, 0, 0);
}

__global__ __launch_bounds__(512, 8) void decoder_f32(
    const float* __restrict__ prev_outputs,
    const void*  __restrict__ prev_is_active,
    const int*   __restrict__ parent_indices,
    const float* __restrict__ Wt,
    const float* __restrict__ bias,
    float*       __restrict__ out)
{
    __shared__ float sbuf[2][MAPB];

    const int k    = blockIdx.x;
    const int tid  = threadIdx.x;
    const int lane = tid & 63;
    const int wv   = tid >> 6;
    const int r0   = wv * 8;

    bool bytemode = false;
    {
        const unsigned* sv = (const unsigned*)prev_is_active;
        #pragma unroll
        for (int i = 0; i < 16; ++i)
            if (sv[i] > 1u) bytemode = true;
    }

    const int* pidx = parent_indices + k * FAN_IN;
    int cnt = 0;
    #pragma unroll
    for (int i = 0; i < FAN_IN; ++i) {
        int p = pidx[i];
        int f;
        if (bytemode) f = (((const unsigned char*)prev_is_active)[p] != 0);
        else          f = (((const int*)prev_is_active)[p] != 0);
        cnt += f;
    }
    const bool active = (cnt >= THRESH);

    const size_t obase = (size_t)k * MAPB;
    if (tid == 0)
        out[(size_t)KN * MAPB + k] = active ? 1.0f : 0.0f;

    if (!active) {
        float4 z = make_float4(0.f, 0.f, 0.f, 0.f);
        float4* o4 = (float4*)(out + obase);
        o4[tid]       = z;
        o4[tid + 512] = z;
        return;
    }

    const float mT = (wv > 0) ? 1.0f : 0.0f;
    const float mB = (wv < 7) ? 1.0f : 0.0f;
    const int   rT = (wv > 0) ? r0 - 1 : 0;
    const int   rB = (wv < 7) ? r0 + 8 : 63;

    const float* wbase = Wt + (size_t)k * FAN_IN * 9;

    float acc[8];
    #pragma unroll
    for (int s = 0; s < 8; ++s) acc[s] = 0.0f;

#define STAGE(b, ch)                                                          \
    {                                                                         \
        const float* g = prev_outputs + (size_t)pidx[ch] * MAPB;              \
        gload_lds16f(g + tid * 4,        &sbuf[b][wv * 256]);                 \
        gload_lds16f(g + 2048 + tid * 4, &sbuf[b][2048 + wv * 256]);          \
    }

    STAGE(0, 0);
    __syncthreads();

    #pragma unroll 2
    for (int ch = 0; ch < FAN_IN; ++ch) {
        if (ch + 1 < FAN_IN) STAGE((ch + 1) & 1, ch + 1);

        const float* sb = sbuf[ch & 1];
        const float* w  = wbase + ch * 9;
        const float wl0 = w[0], wc0 = w[1], wr0 = w[2];
        const float wl1 = w[3], wc1 = w[4], wr1 = w[5];
        const float wl2 = w[6], wc2 = w[7], wr2 = w[8];

        float v[10], l[10], r[10];
        v[0] = sb[rT * NSP + lane] * mT;
        #pragma unroll
        for (int j = 1; j <= 8; ++j) v[j] = sb[(r0 - 1 + j) * NSP + lane];
        v[9] = sb[rB * NSP + lane] * mB;
        #pragma unroll
        for (int j = 0; j < 10; ++j) { l[j] = dpp_wshr1(v[j]); r[j] = dpp_wshl1(v[j]); }

        #pragma unroll
        for (int s = 0; s < 8; ++s) {
            float a = acc[s];
            a = fmaf(wl0, l[s],     fmaf(wc0, v[s],     fmaf(wr0, r[s],     a)));
            a = fmaf(wl1, l[s + 1], fmaf(wc1, v[s + 1], fmaf(wr1, r[s + 1], a)));
            a = fmaf(wl2, l[s + 2], fmaf(wc2, v[s + 2], fmaf(wr2, r[s + 2], a)));
            acc[s] = a;
        }

        if (ch + 1 < FAN_IN) __syncthreads();
    }
#undef STAGE

    const float bk = bias[k];
    #pragma unroll
    for (int s = 0; s < 8; ++s)
        out[obase + (size_t)(r0 + s) * NSP + lane] = tanh_fast(acc[s] + bk);
}

extern "C" void kernel_launch(void* const* d_in, const int* in_sizes, int n_in,
                              void* d_out, int out_size, void* d_ws, size_t ws_size,
                              hipStream_t stream) {
    const float* prev_outputs   = (const float*)d_in[0];
    const void*  prev_is_active = d_in[1];
    const int*   parent_indices = (const int*)d_in[2];
    const float* Wt             = (const float*)d_in[3];
    const float* bias           = (const float*)d_in[4];
    float*       out            = (float*)d_out;

    const size_t need = (size_t)KN * MAPB * sizeof(unsigned short);  // 8 MB
    if (ws_size >= need) {
        unsigned short* maps16 = (unsigned short*)d_ws;
        compress_kernel<<<dim3(KN * MAPB / (256 * 4)), dim3(256), 0, stream>>>(
            prev_outputs, maps16);
        decoder_bf16<<<dim3(KN * 2), dim3(256), 0, stream>>>(
            maps16, prev_is_active, parent_indices, Wt, bias, out);
    } else {
        decoder_f32<<<dim3(KN), dim3(512), 0, stream>>>(
            prev_outputs, prev_is_active, parent_indices, Wt, bias, out);
    }
}